// Round 6
// baseline (158.268 us; speedup 1.0000x reference)
//
#include <hip/hip_runtime.h>
#include <math.h>

#define TPB 256

// XOR-swizzle on linear LDS byte offset A (tile = 8 rows x 1024 f32 = 32 KB).
// key = ((A>>8)^(A>>11))&7 applied to slot bits [4:7).
// swz does NOT commute with '+': within a run whose unswizzled base has bits
// 4-6 clear and whose key bits are constant, swz(A+16k) = swz(A)^16k.
__device__ __forceinline__ unsigned swz(unsigned A) {
    return A ^ ((((A >> 8) ^ (A >> 11)) & 7u) << 4);
}

__device__ __forceinline__ float4 ldsrd(const char* ldsb, unsigned A) {
    return *(const float4*)(ldsb + A);
}

// One stage of block size N (512/256/128) in LDS. Oct-task per thread:
// 8 consecutive pair-indices in both halves of one block -> 32 outputs.
// BARRIER-FREE: each wave owns its two rows exclusively; a wave's DS
// instructions execute in order, so all cross-lane RAW/WAR hazards through
// LDS are ordered without __syncthreads.
template<int N>
__device__ __forceinline__ void lds_stage(char* ldsb, unsigned rb, unsigned tt,
                                          float p, float p1, float p2) {
    constexpr unsigned H = N / 2;
    constexpr int L2 = (N == 512) ? 4 : (N == 256) ? 3 : 2;   // log2(N/32)
    const unsigned b  = tt >> L2;
    const unsigned s  = tt & ((N / 32) - 1);
    const unsigned u0 = s * 8u;
    const unsigned bc = b * (unsigned)N;

    const unsigned Aj0  = swz(rb + 4u * (bc + u0));
    const unsigned Aj1  = swz(rb + 4u * (bc + H + u0));
    const unsigned Ajm0 = swz(rb + 4u * (bc + H - 8 - u0));
    const unsigned Ajm1 = swz(rb + 4u * (bc + N - 8 - u0));
    const unsigned Ae   = swz(rb + 4u * (bc + 2 * u0));
    const unsigned Aem  = swz(rb + 4u * (bc + 2 * H - 16 - 2 * u0));

    float j0[8], j1[8], jm0[8], jm1[8], e[16], em[16];
    *(float4*)&j0[0]  = ldsrd(ldsb, Aj0);        *(float4*)&j0[4]  = ldsrd(ldsb, Aj0 ^ 16u);
    *(float4*)&j1[0]  = ldsrd(ldsb, Aj1);        *(float4*)&j1[4]  = ldsrd(ldsb, Aj1 ^ 16u);
    *(float4*)&jm0[0] = ldsrd(ldsb, Ajm0);       *(float4*)&jm0[4] = ldsrd(ldsb, Ajm0 ^ 16u);
    *(float4*)&jm1[0] = ldsrd(ldsb, Ajm1);       *(float4*)&jm1[4] = ldsrd(ldsb, Ajm1 ^ 16u);
    *(float4*)&e[0]   = ldsrd(ldsb, Ae);         *(float4*)&e[4]   = ldsrd(ldsb, Ae ^ 16u);
    *(float4*)&e[8]   = ldsrd(ldsb, Ae ^ 32u);   *(float4*)&e[12]  = ldsrd(ldsb, Ae ^ 48u);
    *(float4*)&em[0]  = ldsrd(ldsb, Aem);        *(float4*)&em[4]  = ldsrd(ldsb, Aem ^ 16u);
    *(float4*)&em[8]  = ldsrd(ldsb, Aem ^ 32u);  *(float4*)&em[12] = ldsrd(ldsb, Aem ^ 48u);

    #pragma unroll
    for (int du = 0; du < 8; ++du) {
        {   // lo half
            float yj = j0[du], yjm = jm0[7 - du];
            float yej = e[2 * du], yejm = em[14 - 2 * du];
            float a0 = fmaf(p, yej - yj, yj);
            float a1 = fmaf(p, yejm - yjm, yjm);
            float d  = a1 - a0;
            j0[du]      = fmaf(p1, d, a0);
            jm0[7 - du] = fmaf(p1, -d, a1);
        }
        {   // hi half
            float zj = j1[du], zjm = jm1[7 - du];
            float zej = e[2 * du + 1], zejm = em[15 - 2 * du];
            float a0 = fmaf(p, zej - zj, zj);
            float a1 = fmaf(p, zejm - zjm, zjm);
            float d  = a1 - a0;
            j1[du]      = fmaf(p2, d, a0);
            jm1[7 - du] = fmaf(p2, -d, a1);
        }
    }
    // writes reuse the j-read addresses; same-wave DS ordering -> no barrier
    *(float4*)(ldsb + Aj0)          = *(const float4*)&j0[0];
    *(float4*)(ldsb + (Aj0 ^ 16u))  = *(const float4*)&j0[4];
    *(float4*)(ldsb + Aj1)          = *(const float4*)&j1[0];
    *(float4*)(ldsb + (Aj1 ^ 16u))  = *(const float4*)&j1[4];
    *(float4*)(ldsb + Ajm0)         = *(const float4*)&jm0[0];
    *(float4*)(ldsb + (Ajm0 ^ 16u)) = *(const float4*)&jm0[4];
    *(float4*)(ldsb + Ajm1)         = *(const float4*)&jm1[0];
    *(float4*)(ldsb + (Ajm1 ^ 16u)) = *(const float4*)&jm1[4];
}

// Stage of block size N <= 32 fully inside one thread's 32-float chunk.
template<int N>
__device__ __forceinline__ void reg_stage(float* arr, float p, float p1, float p2) {
    constexpr int H = N / 2;
    float tmp[32];
    #pragma unroll
    for (int bb = 0; bb < 32; bb += N) {
        #pragma unroll
        for (int u = 0; u < N / 4; ++u) {
            {   // lo half pair
                int j = bb + u, jm = bb + H - 1 - u;
                int ej = bb + 2 * u, ejm = bb + 2 * H - 2 - 2 * u;
                float a0 = fmaf(p, arr[ej]  - arr[j],  arr[j]);
                float a1 = fmaf(p, arr[ejm] - arr[jm], arr[jm]);
                tmp[j]  = fmaf(p1, a1 - a0, a0);
                tmp[jm] = fmaf(p1, a0 - a1, a1);
            }
            {   // hi half pair
                int j = bb + H + u, jm = bb + 2 * H - 1 - u;
                int ej = bb + 2 * u + 1, ejm = bb + 2 * H - 1 - 2 * u;
                float a0 = fmaf(p, arr[ej]  - arr[j],  arr[j]);
                float a1 = fmaf(p, arr[ejm] - arr[jm], arr[jm]);
                tmp[j]  = fmaf(p2, a1 - a0, a0);
                tmp[jm] = fmaf(p2, a0 - a1, a1);
            }
        }
    }
    #pragma unroll
    for (int v = 0; v < 32; ++v) arr[v] = tmp[v];
}

__global__ void bpp_prep(const float* __restrict__ logits, float* __restrict__ sp) {
    int i = threadIdx.x;
    if (i < 27) sp[i] = 1.0f / (1.0f + expf(-logits[i]));
}

template<bool USE_WS>
__global__ __launch_bounds__(TPB) void bpp_main(const float* __restrict__ x,
                                                float* __restrict__ out,
                                                const float* __restrict__ spws,
                                                const float* __restrict__ logits) {
    __shared__ float lds[8 * 1024];
    char* ldsb = (char*)lds;
    const unsigned t = threadIdx.x;
    const size_t gbase = (size_t)blockIdx.x * (8 * 1024);

    float prl[27];
    if constexpr (!USE_WS) {
        #pragma unroll
        for (int i = 0; i < 27; ++i) prl[i] = 1.0f / (1.0f + expf(-logits[i]));
    }
    #define PV(i) (USE_WS ? spws[(i)] : prl[(i)])

    const unsigned w = t >> 6, l = t & 63u;
    const unsigned row = t >> 5, tt = t & 31u;   // row = 2w + (l>>5): wave-local
    const unsigned rb = row * 4096u;

    // ---- Phase 1: stage n=1024 fused with the global load (no LDS entry copy).
    // j-runs are coalesced; e/em runs re-read the same row out of L1.
    {
        const float* __restrict__ gr = x + gbase + row * 1024u;
        const float p = PV(24), p1 = PV(25), p2 = PV(26);

        float j0[8], j1[8], jm0[8], jm1[8], e[16], em[16];
        #define LD4(dst, off) *(float4*)&(dst) = *(const float4*)(gr + (off))
        LD4(j0[0],  8u * tt);            LD4(j0[4],  8u * tt + 4u);
        LD4(j1[0],  512u + 8u * tt);     LD4(j1[4],  516u + 8u * tt);
        LD4(jm0[0], 504u - 8u * tt);     LD4(jm0[4], 508u - 8u * tt);
        LD4(jm1[0], 1016u - 8u * tt);    LD4(jm1[4], 1020u - 8u * tt);
        LD4(e[0],   16u * tt);           LD4(e[4],   16u * tt + 4u);
        LD4(e[8],   16u * tt + 8u);      LD4(e[12],  16u * tt + 12u);
        LD4(em[0],  1008u - 16u * tt);   LD4(em[4],  1012u - 16u * tt);
        LD4(em[8],  1016u - 16u * tt);   LD4(em[12], 1020u - 16u * tt);
        #undef LD4

        #pragma unroll
        for (int du = 0; du < 8; ++du) {
            {
                float yj = j0[du], yjm = jm0[7 - du];
                float yej = e[2 * du], yejm = em[14 - 2 * du];
                float a0 = fmaf(p, yej - yj, yj);
                float a1 = fmaf(p, yejm - yjm, yjm);
                float d  = a1 - a0;
                j0[du]      = fmaf(p1, d, a0);
                jm0[7 - du] = fmaf(p1, -d, a1);
            }
            {
                float zj = j1[du], zjm = jm1[7 - du];
                float zej = e[2 * du + 1], zejm = em[15 - 2 * du];
                float a0 = fmaf(p, zej - zj, zj);
                float a1 = fmaf(p, zejm - zjm, zjm);
                float d  = a1 - a0;
                j1[du]      = fmaf(p2, d, a0);
                jm1[7 - du] = fmaf(p2, -d, a1);
            }
        }
        const unsigned Aj0  = swz(rb + 32u * tt);
        const unsigned Aj1  = swz(rb + 2048u + 32u * tt);
        const unsigned Ajm0 = swz(rb + 2016u - 32u * tt);
        const unsigned Ajm1 = swz(rb + 4064u - 32u * tt);
        *(float4*)(ldsb + Aj0)          = *(const float4*)&j0[0];
        *(float4*)(ldsb + (Aj0 ^ 16u))  = *(const float4*)&j0[4];
        *(float4*)(ldsb + Aj1)          = *(const float4*)&j1[0];
        *(float4*)(ldsb + (Aj1 ^ 16u))  = *(const float4*)&j1[4];
        *(float4*)(ldsb + Ajm0)         = *(const float4*)&jm0[0];
        *(float4*)(ldsb + (Ajm0 ^ 16u)) = *(const float4*)&jm0[4];
        *(float4*)(ldsb + Ajm1)         = *(const float4*)&jm1[0];
        *(float4*)(ldsb + (Ajm1 ^ 16u)) = *(const float4*)&jm1[4];
    }
    // no barrier: same-wave DS ordering

    // ---- Phases 2-4: stages 512/256/128 in LDS, barrier-free ----
    lds_stage<512>(ldsb, rb, tt, PV(21), PV(22), PV(23));
    lds_stage<256>(ldsb, rb, tt, PV(18), PV(19), PV(20));
    lds_stage<128>(ldsb, rb, tt, PV(15), PV(16), PV(17));

    // ---- Phase 5: stage 64 + reg stages 32..4 + direct global store ----
    // Wave-local remap: lane l -> row 2w+(l&1)... within the wave's 2 rows.
    // half h5 = l>>5 is only half-wave-uniform -> branchless via selects.
    {
        const unsigned m5 = l & 31u;
        const unsigned r5 = 2u * w + (m5 & 1u);
        const unsigned b5 = m5 >> 1;
        const unsigned h5 = l >> 5;
        const unsigned base = r5 * 4096u + b5 * 256u + h5 * 128u; // bits 4-6 clear
        const unsigned So = swz(base);
        const unsigned St = So ^ 128u;   // other half: bit 7 flip, key unchanged
        float own[32], oth[32];
        #pragma unroll
        for (int k = 0; k < 8; ++k) {
            *(float4*)&own[4 * k] = ldsrd(ldsb, So ^ (16u * k));
            *(float4*)&oth[4 * k] = ldsrd(ldsb, St ^ (16u * k));
        }
        const float p = PV(12);
        const float q64 = h5 ? PV(14) : PV(13);
        float o[32];
        #pragma unroll
        for (int u = 0; u < 16; ++u) {
            float eja = h5 ? oth[2 * u + 1]  : own[2 * u];
            float ejb = h5 ? own[31 - 2 * u] : oth[30 - 2 * u];
            float yj = own[u], yjm = own[31 - u];
            float a0 = fmaf(p, eja - yj, yj);
            float a1 = fmaf(p, ejb - yjm, yjm);
            float d  = a1 - a0;
            o[u]      = fmaf(q64, d, a0);
            o[31 - u] = fmaf(q64, -d, a1);
        }
        reg_stage<32>(o, PV(9), PV(10), PV(11));
        reg_stage<16>(o, PV(6), PV(7),  PV(8));
        reg_stage< 8>(o, PV(3), PV(4),  PV(5));
        reg_stage< 4>(o, PV(0), PV(1),  PV(2));

        float* __restrict__ go = out + gbase + r5 * 1024u + b5 * 64u + h5 * 32u;
        #pragma unroll
        for (int k = 0; k < 8; ++k)
            *(float4*)(go + 4 * k) = *(const float4*)&o[4 * k];
    }
    #undef PV
}

extern "C" void kernel_launch(void* const* d_in, const int* in_sizes, int n_in,
                              void* d_out, int out_size, void* d_ws, size_t ws_size,
                              hipStream_t stream) {
    const float* x      = (const float*)d_in[0];
    const float* logits = (const float*)d_in[1];
    float* out = (float*)d_out;
    int rows = in_sizes[0] / 1024;
    int grid = rows / 8;
    if (ws_size >= 27 * sizeof(float)) {
        float* sp = (float*)d_ws;
        bpp_prep<<<dim3(1), dim3(32), 0, stream>>>(logits, sp);
        bpp_main<true><<<dim3(grid), dim3(TPB), 0, stream>>>(x, out, sp, logits);
    } else {
        bpp_main<false><<<dim3(grid), dim3(TPB), 0, stream>>>(x, out, nullptr, logits);
    }
}

// Round 7
// 131.028 us; speedup vs baseline: 1.2079x; 1.2079x over previous
//
#include <hip/hip_runtime.h>
#include <math.h>

#define TPB 256

// XOR-swizzle on linear LDS byte offset A (tile = 8 rows x 1024 f32 = 32 KB).
// key = ((A>>8)^(A>>11))&7 applied to slot bits [4:7).
// swz does NOT commute with '+': within a run whose unswizzled base has bits
// 4-6 clear and whose key bits are constant, swz(A+16k) = swz(A)^16k.
// Also: swz(X^128) = swz(X)^128 (bit 7 is not part of the key).
__device__ __forceinline__ unsigned swz(unsigned A) {
    return A ^ ((((A >> 8) ^ (A >> 11)) & 7u) << 4);
}

__device__ __forceinline__ float4 ldsrd(const char* ldsb, unsigned A) {
    return *(const float4*)(ldsb + A);
}

// One stage of block size N (512/256/128) in LDS. Oct-task per thread:
// 8 consecutive pair-indices in both halves of one block -> 32 outputs.
// BARRIER-FREE: each wave owns its two rows exclusively; a wave's DS
// instructions execute in order, so all cross-lane RAW/WAR hazards through
// LDS are ordered without __syncthreads.
template<int N>
__device__ __forceinline__ void lds_stage(char* ldsb, unsigned rb, unsigned tt,
                                          float p, float p1, float p2) {
    constexpr unsigned H = N / 2;
    constexpr int L2 = (N == 512) ? 4 : (N == 256) ? 3 : 2;   // log2(N/32)
    const unsigned b  = tt >> L2;
    const unsigned s  = tt & ((N / 32) - 1);
    const unsigned u0 = s * 8u;
    const unsigned bc = b * (unsigned)N;

    const unsigned Aj0  = swz(rb + 4u * (bc + u0));
    const unsigned Aj1  = swz(rb + 4u * (bc + H + u0));
    const unsigned Ajm0 = swz(rb + 4u * (bc + H - 8 - u0));
    const unsigned Ajm1 = swz(rb + 4u * (bc + N - 8 - u0));
    const unsigned Ae   = swz(rb + 4u * (bc + 2 * u0));
    const unsigned Aem  = swz(rb + 4u * (bc + 2 * H - 16 - 2 * u0));

    float j0[8], j1[8], jm0[8], jm1[8], e[16], em[16];
    *(float4*)&j0[0]  = ldsrd(ldsb, Aj0);        *(float4*)&j0[4]  = ldsrd(ldsb, Aj0 ^ 16u);
    *(float4*)&j1[0]  = ldsrd(ldsb, Aj1);        *(float4*)&j1[4]  = ldsrd(ldsb, Aj1 ^ 16u);
    *(float4*)&jm0[0] = ldsrd(ldsb, Ajm0);       *(float4*)&jm0[4] = ldsrd(ldsb, Ajm0 ^ 16u);
    *(float4*)&jm1[0] = ldsrd(ldsb, Ajm1);       *(float4*)&jm1[4] = ldsrd(ldsb, Ajm1 ^ 16u);
    *(float4*)&e[0]   = ldsrd(ldsb, Ae);         *(float4*)&e[4]   = ldsrd(ldsb, Ae ^ 16u);
    *(float4*)&e[8]   = ldsrd(ldsb, Ae ^ 32u);   *(float4*)&e[12]  = ldsrd(ldsb, Ae ^ 48u);
    *(float4*)&em[0]  = ldsrd(ldsb, Aem);        *(float4*)&em[4]  = ldsrd(ldsb, Aem ^ 16u);
    *(float4*)&em[8]  = ldsrd(ldsb, Aem ^ 32u);  *(float4*)&em[12] = ldsrd(ldsb, Aem ^ 48u);

    #pragma unroll
    for (int du = 0; du < 8; ++du) {
        {   // lo half
            float yj = j0[du], yjm = jm0[7 - du];
            float yej = e[2 * du], yejm = em[14 - 2 * du];
            float a0 = fmaf(p, yej - yj, yj);
            float a1 = fmaf(p, yejm - yjm, yjm);
            float d  = a1 - a0;
            j0[du]      = fmaf(p1, d, a0);
            jm0[7 - du] = fmaf(p1, -d, a1);
        }
        {   // hi half
            float zj = j1[du], zjm = jm1[7 - du];
            float zej = e[2 * du + 1], zejm = em[15 - 2 * du];
            float a0 = fmaf(p, zej - zj, zj);
            float a1 = fmaf(p, zejm - zjm, zjm);
            float d  = a1 - a0;
            j1[du]      = fmaf(p2, d, a0);
            jm1[7 - du] = fmaf(p2, -d, a1);
        }
    }
    // writes reuse the j-read addresses; same-wave DS ordering -> no barrier
    *(float4*)(ldsb + Aj0)          = *(const float4*)&j0[0];
    *(float4*)(ldsb + (Aj0 ^ 16u))  = *(const float4*)&j0[4];
    *(float4*)(ldsb + Aj1)          = *(const float4*)&j1[0];
    *(float4*)(ldsb + (Aj1 ^ 16u))  = *(const float4*)&j1[4];
    *(float4*)(ldsb + Ajm0)         = *(const float4*)&jm0[0];
    *(float4*)(ldsb + (Ajm0 ^ 16u)) = *(const float4*)&jm0[4];
    *(float4*)(ldsb + Ajm1)         = *(const float4*)&jm1[0];
    *(float4*)(ldsb + (Ajm1 ^ 16u)) = *(const float4*)&jm1[4];
}

// Stage of block size N <= 32 fully inside one thread's 32-float chunk.
template<int N>
__device__ __forceinline__ void reg_stage(float* arr, float p, float p1, float p2) {
    constexpr int H = N / 2;
    float tmp[32];
    #pragma unroll
    for (int bb = 0; bb < 32; bb += N) {
        #pragma unroll
        for (int u = 0; u < N / 4; ++u) {
            {   // lo half pair
                int j = bb + u, jm = bb + H - 1 - u;
                int ej = bb + 2 * u, ejm = bb + 2 * H - 2 - 2 * u;
                float a0 = fmaf(p, arr[ej]  - arr[j],  arr[j]);
                float a1 = fmaf(p, arr[ejm] - arr[jm], arr[jm]);
                tmp[j]  = fmaf(p1, a1 - a0, a0);
                tmp[jm] = fmaf(p1, a0 - a1, a1);
            }
            {   // hi half pair
                int j = bb + H + u, jm = bb + 2 * H - 1 - u;
                int ej = bb + 2 * u + 1, ejm = bb + 2 * H - 1 - 2 * u;
                float a0 = fmaf(p, arr[ej]  - arr[j],  arr[j]);
                float a1 = fmaf(p, arr[ejm] - arr[jm], arr[jm]);
                tmp[j]  = fmaf(p2, a1 - a0, a0);
                tmp[jm] = fmaf(p2, a0 - a1, a1);
            }
        }
    }
    #pragma unroll
    for (int v = 0; v < 32; ++v) arr[v] = tmp[v];
}

__global__ void bpp_prep(const float* __restrict__ logits, float* __restrict__ sp) {
    int i = threadIdx.x;
    if (i < 27) sp[i] = 1.0f / (1.0f + expf(-logits[i]));
}

template<bool USE_WS>
__global__ __launch_bounds__(TPB) void bpp_main(const float* __restrict__ x,
                                                float* __restrict__ out,
                                                const float* __restrict__ spws,
                                                const float* __restrict__ logits) {
    __shared__ float lds[8 * 1024];
    char* ldsb = (char*)lds;
    const unsigned t = threadIdx.x;
    const size_t gbase = (size_t)blockIdx.x * (8 * 1024);

    float prl[27];
    if constexpr (!USE_WS) {
        #pragma unroll
        for (int i = 0; i < 27; ++i) prl[i] = 1.0f / (1.0f + expf(-logits[i]));
    }
    #define PV(i) (USE_WS ? spws[(i)] : prl[(i)])

    const unsigned w = t >> 6, l = t & 63u;     // wave id, lane id
    const unsigned wbase = w * 8192u;           // wave's 2-row LDS segment (bytes)

    // ---- entry: wave-local coalesced global -> LDS (1 KB per instruction) ----
    {
        const float4* __restrict__ gin = (const float4*)(x + gbase) + w * 512u + l;
        #pragma unroll
        for (int k = 0; k < 8; ++k) {
            float4 v = gin[k * 64];
            unsigned A = wbase + (unsigned)k * 1024u + l * 16u;
            *(float4*)(ldsb + swz(A)) = v;
        }
    }
    // no barrier: same-wave DS ordering covers the stage-1024 reads below

    const unsigned row = t >> 5, tt = t & 31u;  // row = 2w + (l>>5): wave-local
    const unsigned rb = row * 4096u;

    // ---- stages n = 1024..128 in LDS (logits rows 8..5), barrier-free ----
    {
        // stage 1024 (b=0 specialization of lds_stage)
        constexpr unsigned N = 1024, H = 512;
        const unsigned u0 = tt * 8u;
        const unsigned Aj0  = swz(rb + 4u * u0);
        const unsigned Aj1  = swz(rb + 4u * (H + u0));
        const unsigned Ajm0 = swz(rb + 4u * (H - 8 - u0));
        const unsigned Ajm1 = swz(rb + 4u * (N - 8 - u0));
        const unsigned Ae   = swz(rb + 4u * (2 * u0));
        const unsigned Aem  = swz(rb + 4u * (2 * H - 16 - 2 * u0));
        const float p = PV(24), p1 = PV(25), p2 = PV(26);

        float j0[8], j1[8], jm0[8], jm1[8], e[16], em[16];
        *(float4*)&j0[0]  = ldsrd(ldsb, Aj0);        *(float4*)&j0[4]  = ldsrd(ldsb, Aj0 ^ 16u);
        *(float4*)&j1[0]  = ldsrd(ldsb, Aj1);        *(float4*)&j1[4]  = ldsrd(ldsb, Aj1 ^ 16u);
        *(float4*)&jm0[0] = ldsrd(ldsb, Ajm0);       *(float4*)&jm0[4] = ldsrd(ldsb, Ajm0 ^ 16u);
        *(float4*)&jm1[0] = ldsrd(ldsb, Ajm1);       *(float4*)&jm1[4] = ldsrd(ldsb, Ajm1 ^ 16u);
        *(float4*)&e[0]   = ldsrd(ldsb, Ae);         *(float4*)&e[4]   = ldsrd(ldsb, Ae ^ 16u);
        *(float4*)&e[8]   = ldsrd(ldsb, Ae ^ 32u);   *(float4*)&e[12]  = ldsrd(ldsb, Ae ^ 48u);
        *(float4*)&em[0]  = ldsrd(ldsb, Aem);        *(float4*)&em[4]  = ldsrd(ldsb, Aem ^ 16u);
        *(float4*)&em[8]  = ldsrd(ldsb, Aem ^ 32u);  *(float4*)&em[12] = ldsrd(ldsb, Aem ^ 48u);

        #pragma unroll
        for (int du = 0; du < 8; ++du) {
            {
                float yj = j0[du], yjm = jm0[7 - du];
                float yej = e[2 * du], yejm = em[14 - 2 * du];
                float a0 = fmaf(p, yej - yj, yj);
                float a1 = fmaf(p, yejm - yjm, yjm);
                float d  = a1 - a0;
                j0[du]      = fmaf(p1, d, a0);
                jm0[7 - du] = fmaf(p1, -d, a1);
            }
            {
                float zj = j1[du], zjm = jm1[7 - du];
                float zej = e[2 * du + 1], zejm = em[15 - 2 * du];
                float a0 = fmaf(p, zej - zj, zj);
                float a1 = fmaf(p, zejm - zjm, zjm);
                float d  = a1 - a0;
                j1[du]      = fmaf(p2, d, a0);
                jm1[7 - du] = fmaf(p2, -d, a1);
            }
        }
        *(float4*)(ldsb + Aj0)          = *(const float4*)&j0[0];
        *(float4*)(ldsb + (Aj0 ^ 16u))  = *(const float4*)&j0[4];
        *(float4*)(ldsb + Aj1)          = *(const float4*)&j1[0];
        *(float4*)(ldsb + (Aj1 ^ 16u))  = *(const float4*)&j1[4];
        *(float4*)(ldsb + Ajm0)         = *(const float4*)&jm0[0];
        *(float4*)(ldsb + (Ajm0 ^ 16u)) = *(const float4*)&jm0[4];
        *(float4*)(ldsb + Ajm1)         = *(const float4*)&jm1[0];
        *(float4*)(ldsb + (Ajm1 ^ 16u)) = *(const float4*)&jm1[4];
    }
    lds_stage<512>(ldsb, rb, tt, PV(21), PV(22), PV(23));
    lds_stage<256>(ldsb, rb, tt, PV(18), PV(19), PV(20));
    lds_stage<128>(ldsb, rb, tt, PV(15), PV(16), PV(17));

    // ---- fused tail: stage 64 in registers + reg stages 32..4 ----
    // Thread owns chunk tt (cols [32tt, 32tt+32)); its 64-block partner half
    // is chunk tt^1. q = tt&1 selects lo/hi-half math (branchless selects,
    // formulation correctness-verified in the round-6 run).
    {
        const unsigned q = tt & 1u;
        const unsigned Aown = swz(rb + 128u * tt);  // 128B-aligned, key const
        const unsigned Aoth = Aown ^ 128u;          // partner: bit7 not in key
        float own[32], oth[32];
        #pragma unroll
        for (int k = 0; k < 8; ++k) {
            *(float4*)&own[4 * k] = ldsrd(ldsb, Aown ^ (16u * k));
            *(float4*)&oth[4 * k] = ldsrd(ldsb, Aoth ^ (16u * k));
        }
        const float p = PV(12);
        const float q64 = q ? PV(14) : PV(13);
        float o[32];
        #pragma unroll
        for (int u = 0; u < 16; ++u) {
            float eja = q ? oth[2 * u + 1]  : own[2 * u];
            float ejb = q ? own[31 - 2 * u] : oth[30 - 2 * u];
            float yj = own[u], yjm = own[31 - u];
            float a0 = fmaf(p, eja - yj, yj);
            float a1 = fmaf(p, ejb - yjm, yjm);
            float d  = a1 - a0;
            o[u]      = fmaf(q64, d, a0);
            o[31 - u] = fmaf(q64, -d, a1);
        }
        reg_stage<32>(o, PV(9), PV(10), PV(11));
        reg_stage<16>(o, PV(6), PV(7),  PV(8));
        reg_stage< 8>(o, PV(3), PV(4),  PV(5));
        reg_stage< 4>(o, PV(0), PV(1),  PV(2));
        // write back to own chunk (all lanes' reads above precede these writes
        // in the wave's in-order DS stream -> no WAR hazard)
        #pragma unroll
        for (int k = 0; k < 8; ++k)
            *(float4*)(ldsb + (Aown ^ (16u * k))) = *(const float4*)&o[4 * k];
    }

    // ---- exit: wave-local coalesced LDS -> global (1 KB per instruction) ----
    {
        float4* __restrict__ gout = (float4*)(out + gbase) + w * 512u + l;
        #pragma unroll
        for (int k = 0; k < 8; ++k) {
            unsigned A = wbase + (unsigned)k * 1024u + l * 16u;
            gout[k * 64] = *(const float4*)(ldsb + swz(A));
        }
    }
    #undef PV
}

extern "C" void kernel_launch(void* const* d_in, const int* in_sizes, int n_in,
                              void* d_out, int out_size, void* d_ws, size_t ws_size,
                              hipStream_t stream) {
    const float* x      = (const float*)d_in[0];
    const float* logits = (const float*)d_in[1];
    float* out = (float*)d_out;
    int rows = in_sizes[0] / 1024;
    int grid = rows / 8;
    if (ws_size >= 27 * sizeof(float)) {
        float* sp = (float*)d_ws;
        bpp_prep<<<dim3(1), dim3(32), 0, stream>>>(logits, sp);
        bpp_main<true><<<dim3(grid), dim3(TPB), 0, stream>>>(x, out, sp, logits);
    } else {
        bpp_main<false><<<dim3(grid), dim3(TPB), 0, stream>>>(x, out, nullptr, logits);
    }
}

// Round 8
// 123.841 us; speedup vs baseline: 1.2780x; 1.0580x over previous
//
#include <hip/hip_runtime.h>
#include <math.h>

#define TPB 64      // ONE wave per workgroup: no intra-block co-scheduling
#define ROWS 2      // 8 KB LDS per block -> up to 20 blocks/CU

// XOR-swizzle on linear LDS byte offset A (tile = 2 rows x 1024 f32 = 8 KB).
// key = ((A>>8)^(A>>11))&7 applied to slot bits [4:7).
// swz does NOT commute with '+': within a run whose unswizzled base has bits
// 4-6 clear and whose key bits are constant, swz(A+16k) = swz(A)^16k.
// Also: swz(X^128) = swz(X)^128 (bit 7 is not part of the key).
__device__ __forceinline__ unsigned swz(unsigned A) {
    return A ^ ((((A >> 8) ^ (A >> 11)) & 7u) << 4);
}

__device__ __forceinline__ float4 ldsrd(const char* ldsb, unsigned A) {
    return *(const float4*)(ldsb + A);
}

// One stage of block size N (512/256/128) in LDS. Oct-task per thread:
// 8 consecutive pair-indices in both halves of one block -> 32 outputs.
// BARRIER-FREE: the (single) wave owns the whole LDS tile; a wave's DS
// instructions execute in order, so all cross-lane RAW/WAR hazards through
// LDS are ordered without __syncthreads.
template<int N>
__device__ __forceinline__ void lds_stage(char* ldsb, unsigned rb, unsigned tt,
                                          float p, float p1, float p2) {
    constexpr unsigned H = N / 2;
    constexpr int L2 = (N == 512) ? 4 : (N == 256) ? 3 : 2;   // log2(N/32)
    const unsigned b  = tt >> L2;
    const unsigned s  = tt & ((N / 32) - 1);
    const unsigned u0 = s * 8u;
    const unsigned bc = b * (unsigned)N;

    const unsigned Aj0  = swz(rb + 4u * (bc + u0));
    const unsigned Aj1  = swz(rb + 4u * (bc + H + u0));
    const unsigned Ajm0 = swz(rb + 4u * (bc + H - 8 - u0));
    const unsigned Ajm1 = swz(rb + 4u * (bc + N - 8 - u0));
    const unsigned Ae   = swz(rb + 4u * (bc + 2 * u0));
    const unsigned Aem  = swz(rb + 4u * (bc + 2 * H - 16 - 2 * u0));

    float j0[8], j1[8], jm0[8], jm1[8], e[16], em[16];
    *(float4*)&j0[0]  = ldsrd(ldsb, Aj0);        *(float4*)&j0[4]  = ldsrd(ldsb, Aj0 ^ 16u);
    *(float4*)&j1[0]  = ldsrd(ldsb, Aj1);        *(float4*)&j1[4]  = ldsrd(ldsb, Aj1 ^ 16u);
    *(float4*)&jm0[0] = ldsrd(ldsb, Ajm0);       *(float4*)&jm0[4] = ldsrd(ldsb, Ajm0 ^ 16u);
    *(float4*)&jm1[0] = ldsrd(ldsb, Ajm1);       *(float4*)&jm1[4] = ldsrd(ldsb, Ajm1 ^ 16u);
    *(float4*)&e[0]   = ldsrd(ldsb, Ae);         *(float4*)&e[4]   = ldsrd(ldsb, Ae ^ 16u);
    *(float4*)&e[8]   = ldsrd(ldsb, Ae ^ 32u);   *(float4*)&e[12]  = ldsrd(ldsb, Ae ^ 48u);
    *(float4*)&em[0]  = ldsrd(ldsb, Aem);        *(float4*)&em[4]  = ldsrd(ldsb, Aem ^ 16u);
    *(float4*)&em[8]  = ldsrd(ldsb, Aem ^ 32u);  *(float4*)&em[12] = ldsrd(ldsb, Aem ^ 48u);

    #pragma unroll
    for (int du = 0; du < 8; ++du) {
        {   // lo half
            float yj = j0[du], yjm = jm0[7 - du];
            float yej = e[2 * du], yejm = em[14 - 2 * du];
            float a0 = fmaf(p, yej - yj, yj);
            float a1 = fmaf(p, yejm - yjm, yjm);
            float d  = a1 - a0;
            j0[du]      = fmaf(p1, d, a0);
            jm0[7 - du] = fmaf(p1, -d, a1);
        }
        {   // hi half
            float zj = j1[du], zjm = jm1[7 - du];
            float zej = e[2 * du + 1], zejm = em[15 - 2 * du];
            float a0 = fmaf(p, zej - zj, zj);
            float a1 = fmaf(p, zejm - zjm, zjm);
            float d  = a1 - a0;
            j1[du]      = fmaf(p2, d, a0);
            jm1[7 - du] = fmaf(p2, -d, a1);
        }
    }
    // writes reuse the j-read addresses; same-wave DS ordering -> no barrier
    *(float4*)(ldsb + Aj0)          = *(const float4*)&j0[0];
    *(float4*)(ldsb + (Aj0 ^ 16u))  = *(const float4*)&j0[4];
    *(float4*)(ldsb + Aj1)          = *(const float4*)&j1[0];
    *(float4*)(ldsb + (Aj1 ^ 16u))  = *(const float4*)&j1[4];
    *(float4*)(ldsb + Ajm0)         = *(const float4*)&jm0[0];
    *(float4*)(ldsb + (Ajm0 ^ 16u)) = *(const float4*)&jm0[4];
    *(float4*)(ldsb + Ajm1)         = *(const float4*)&jm1[0];
    *(float4*)(ldsb + (Ajm1 ^ 16u)) = *(const float4*)&jm1[4];
}

// Stage of block size N <= 32 fully inside one thread's 32-float chunk.
template<int N>
__device__ __forceinline__ void reg_stage(float* arr, float p, float p1, float p2) {
    constexpr int H = N / 2;
    float tmp[32];
    #pragma unroll
    for (int bb = 0; bb < 32; bb += N) {
        #pragma unroll
        for (int u = 0; u < N / 4; ++u) {
            {   // lo half pair
                int j = bb + u, jm = bb + H - 1 - u;
                int ej = bb + 2 * u, ejm = bb + 2 * H - 2 - 2 * u;
                float a0 = fmaf(p, arr[ej]  - arr[j],  arr[j]);
                float a1 = fmaf(p, arr[ejm] - arr[jm], arr[jm]);
                tmp[j]  = fmaf(p1, a1 - a0, a0);
                tmp[jm] = fmaf(p1, a0 - a1, a1);
            }
            {   // hi half pair
                int j = bb + H + u, jm = bb + 2 * H - 1 - u;
                int ej = bb + 2 * u + 1, ejm = bb + 2 * H - 1 - 2 * u;
                float a0 = fmaf(p, arr[ej]  - arr[j],  arr[j]);
                float a1 = fmaf(p, arr[ejm] - arr[jm], arr[jm]);
                tmp[j]  = fmaf(p2, a1 - a0, a0);
                tmp[jm] = fmaf(p2, a0 - a1, a1);
            }
        }
    }
    #pragma unroll
    for (int v = 0; v < 32; ++v) arr[v] = tmp[v];
}

__global__ void bpp_prep(const float* __restrict__ logits, float* __restrict__ sp) {
    int i = threadIdx.x;
    if (i < 27) sp[i] = 1.0f / (1.0f + expf(-logits[i]));
}

template<bool USE_WS>
__global__ __launch_bounds__(TPB) void bpp_main(const float* __restrict__ x,
                                                float* __restrict__ out,
                                                const float* __restrict__ spws,
                                                const float* __restrict__ logits) {
    __shared__ float lds[ROWS * 1024];
    char* ldsb = (char*)lds;
    const unsigned l = threadIdx.x;             // lane id (block == one wave)
    const size_t gbase = (size_t)blockIdx.x * (ROWS * 1024);

    float prl[27];
    if constexpr (!USE_WS) {
        #pragma unroll
        for (int i = 0; i < 27; ++i) prl[i] = 1.0f / (1.0f + expf(-logits[i]));
    }
    #define PV(i) (USE_WS ? spws[(i)] : prl[(i)])

    // ---- entry: coalesced global -> LDS (1 KB per instruction) ----
    {
        const float4* __restrict__ gin = (const float4*)(x + gbase) + l;
        #pragma unroll
        for (int k = 0; k < 8; ++k) {
            float4 v = gin[k * 64];
            unsigned A = (unsigned)k * 1024u + l * 16u;
            *(float4*)(ldsb + swz(A)) = v;
        }
    }
    // no barrier: same-wave DS ordering covers the stage-1024 reads below

    const unsigned row = l >> 5, tt = l & 31u;
    const unsigned rb = row * 4096u;

    // ---- stages n = 1024..128 in LDS (logits rows 8..5), barrier-free ----
    {
        // stage 1024 (b=0 specialization of lds_stage)
        constexpr unsigned N = 1024, H = 512;
        const unsigned u0 = tt * 8u;
        const unsigned Aj0  = swz(rb + 4u * u0);
        const unsigned Aj1  = swz(rb + 4u * (H + u0));
        const unsigned Ajm0 = swz(rb + 4u * (H - 8 - u0));
        const unsigned Ajm1 = swz(rb + 4u * (N - 8 - u0));
        const unsigned Ae   = swz(rb + 4u * (2 * u0));
        const unsigned Aem  = swz(rb + 4u * (2 * H - 16 - 2 * u0));
        const float p = PV(24), p1 = PV(25), p2 = PV(26);

        float j0[8], j1[8], jm0[8], jm1[8], e[16], em[16];
        *(float4*)&j0[0]  = ldsrd(ldsb, Aj0);        *(float4*)&j0[4]  = ldsrd(ldsb, Aj0 ^ 16u);
        *(float4*)&j1[0]  = ldsrd(ldsb, Aj1);        *(float4*)&j1[4]  = ldsrd(ldsb, Aj1 ^ 16u);
        *(float4*)&jm0[0] = ldsrd(ldsb, Ajm0);       *(float4*)&jm0[4] = ldsrd(ldsb, Ajm0 ^ 16u);
        *(float4*)&jm1[0] = ldsrd(ldsb, Ajm1);       *(float4*)&jm1[4] = ldsrd(ldsb, Ajm1 ^ 16u);
        *(float4*)&e[0]   = ldsrd(ldsb, Ae);         *(float4*)&e[4]   = ldsrd(ldsb, Ae ^ 16u);
        *(float4*)&e[8]   = ldsrd(ldsb, Ae ^ 32u);   *(float4*)&e[12]  = ldsrd(ldsb, Ae ^ 48u);
        *(float4*)&em[0]  = ldsrd(ldsb, Aem);        *(float4*)&em[4]  = ldsrd(ldsb, Aem ^ 16u);
        *(float4*)&em[8]  = ldsrd(ldsb, Aem ^ 32u);  *(float4*)&em[12] = ldsrd(ldsb, Aem ^ 48u);

        #pragma unroll
        for (int du = 0; du < 8; ++du) {
            {
                float yj = j0[du], yjm = jm0[7 - du];
                float yej = e[2 * du], yejm = em[14 - 2 * du];
                float a0 = fmaf(p, yej - yj, yj);
                float a1 = fmaf(p, yejm - yjm, yjm);
                float d  = a1 - a0;
                j0[du]      = fmaf(p1, d, a0);
                jm0[7 - du] = fmaf(p1, -d, a1);
            }
            {
                float zj = j1[du], zjm = jm1[7 - du];
                float zej = e[2 * du + 1], zejm = em[15 - 2 * du];
                float a0 = fmaf(p, zej - zj, zj);
                float a1 = fmaf(p, zejm - zjm, zjm);
                float d  = a1 - a0;
                j1[du]      = fmaf(p2, d, a0);
                jm1[7 - du] = fmaf(p2, -d, a1);
            }
        }
        *(float4*)(ldsb + Aj0)          = *(const float4*)&j0[0];
        *(float4*)(ldsb + (Aj0 ^ 16u))  = *(const float4*)&j0[4];
        *(float4*)(ldsb + Aj1)          = *(const float4*)&j1[0];
        *(float4*)(ldsb + (Aj1 ^ 16u))  = *(const float4*)&j1[4];
        *(float4*)(ldsb + Ajm0)         = *(const float4*)&jm0[0];
        *(float4*)(ldsb + (Ajm0 ^ 16u)) = *(const float4*)&jm0[4];
        *(float4*)(ldsb + Ajm1)         = *(const float4*)&jm1[0];
        *(float4*)(ldsb + (Ajm1 ^ 16u)) = *(const float4*)&jm1[4];
    }
    lds_stage<512>(ldsb, rb, tt, PV(21), PV(22), PV(23));
    lds_stage<256>(ldsb, rb, tt, PV(18), PV(19), PV(20));
    lds_stage<128>(ldsb, rb, tt, PV(15), PV(16), PV(17));

    // ---- fused tail: stage 64 in registers + reg stages 32..4 ----
    // Thread owns chunk tt (cols [32tt, 32tt+32)); its 64-block partner half
    // is chunk tt^1. q = tt&1 selects lo/hi-half math (branchless selects).
    {
        const unsigned q = tt & 1u;
        const unsigned Aown = swz(rb + 128u * tt);  // 128B-aligned, key const
        const unsigned Aoth = Aown ^ 128u;          // partner: bit7 not in key
        float own[32], oth[32];
        #pragma unroll
        for (int k = 0; k < 8; ++k) {
            *(float4*)&own[4 * k] = ldsrd(ldsb, Aown ^ (16u * k));
            *(float4*)&oth[4 * k] = ldsrd(ldsb, Aoth ^ (16u * k));
        }
        const float p = PV(12);
        const float q64 = q ? PV(14) : PV(13);
        float o[32];
        #pragma unroll
        for (int u = 0; u < 16; ++u) {
            float eja = q ? oth[2 * u + 1]  : own[2 * u];
            float ejb = q ? own[31 - 2 * u] : oth[30 - 2 * u];
            float yj = own[u], yjm = own[31 - u];
            float a0 = fmaf(p, eja - yj, yj);
            float a1 = fmaf(p, ejb - yjm, yjm);
            float d  = a1 - a0;
            o[u]      = fmaf(q64, d, a0);
            o[31 - u] = fmaf(q64, -d, a1);
        }
        reg_stage<32>(o, PV(9), PV(10), PV(11));
        reg_stage<16>(o, PV(6), PV(7),  PV(8));
        reg_stage< 8>(o, PV(3), PV(4),  PV(5));
        reg_stage< 4>(o, PV(0), PV(1),  PV(2));
        // write back to own chunk (all lanes' reads above precede these writes
        // in the wave's in-order DS stream -> no WAR hazard)
        #pragma unroll
        for (int k = 0; k < 8; ++k)
            *(float4*)(ldsb + (Aown ^ (16u * k))) = *(const float4*)&o[4 * k];
    }

    // ---- exit: coalesced LDS -> global (1 KB per instruction) ----
    {
        float4* __restrict__ gout = (float4*)(out + gbase) + l;
        #pragma unroll
        for (int k = 0; k < 8; ++k) {
            unsigned A = (unsigned)k * 1024u + l * 16u;
            gout[k * 64] = *(const float4*)(ldsb + swz(A));
        }
    }
    #undef PV
}

extern "C" void kernel_launch(void* const* d_in, const int* in_sizes, int n_in,
                              void* d_out, int out_size, void* d_ws, size_t ws_size,
                              hipStream_t stream) {
    const float* x      = (const float*)d_in[0];
    const float* logits = (const float*)d_in[1];
    float* out = (float*)d_out;
    int rows = in_sizes[0] / 1024;
    int grid = rows / ROWS;
    if (ws_size >= 27 * sizeof(float)) {
        float* sp = (float*)d_ws;
        bpp_prep<<<dim3(1), dim3(32), 0, stream>>>(logits, sp);
        bpp_main<true><<<dim3(grid), dim3(TPB), 0, stream>>>(x, out, sp, logits);
    } else {
        bpp_main<false><<<dim3(grid), dim3(TPB), 0, stream>>>(x, out, nullptr, logits);
    }
}